// Round 16
// baseline (370.909 us; speedup 1.0000x reference)
//
#include <hip/hip_runtime.h>

#define DIM 128
#define WPAD 136   // DIM + 8 ushorts pad -> 16B-aligned rows, 2-way-free banks
typedef unsigned int uint;
typedef unsigned short ushort;

#define RFL __builtin_amdgcn_readfirstlane

typedef __attribute__((ext_vector_type(8))) short bf16x8;
typedef __attribute__((ext_vector_type(4))) float f32x4;

// bf16 pack (RNE)
__device__ __forceinline__ ushort f2bf(float x) {
    uint u = __float_as_uint(x);
    u = u + 0x7FFFu + ((u >> 16) & 1u);
    return (ushort)(u >> 16);
}

__device__ __forceinline__ int src_bucket(int s, int Q) {
    int p = s / Q;
    return p > 3 ? 3 : p;
}

// ---------------- degree count into 4 src-range buckets per dst ----------------
__global__ __launch_bounds__(256) void k_count4(const int* __restrict__ src,
                                                const int* __restrict__ dst,
                                                int* __restrict__ deg4, int E, int Q) {
    int t = blockIdx.x * 256 + threadIdx.x;
    if (t < E) {
        int p = src_bucket(src[t], Q);
        atomicAdd(&deg4[(dst[t] << 2) + p], 1);
    }
}

// dinv from bucket-sum (deg = sum of node's 4 bucket counts via rowptr4 diff)
__global__ __launch_bounds__(256) void k_dinv(const int* __restrict__ rowptr4,
                                              float* __restrict__ dinv, int N) {
    int t = blockIdx.x * 256 + threadIdx.x;
    if (t < N) {
        int deg = rowptr4[(t << 2) + 4] - rowptr4[t << 2];
        dinv[t] = rsqrtf((float)(deg + 1));  // +1 = self-loop
    }
}

// ---------------- parallel exclusive scan over M=4N entries ----------------
__global__ __launch_bounds__(256) void k_scanA(const int* __restrict__ deg,
                                               int* __restrict__ rowptr,
                                               int* __restrict__ segsum, int M) {
    int i = blockIdx.x * 256 + threadIdx.x;
    int v = (i < M) ? deg[i] : 0;
    __shared__ int ps[256];
    ps[threadIdx.x] = v;
    __syncthreads();
    for (int off = 1; off < 256; off <<= 1) {
        int u = (threadIdx.x >= off) ? ps[threadIdx.x - off] : 0;
        __syncthreads();
        ps[threadIdx.x] += u;
        __syncthreads();
    }
    if (i < M) rowptr[i] = ps[threadIdx.x] - v;   // exclusive within block
    if (threadIdx.x == 255) segsum[blockIdx.x] = ps[255];
}

__global__ __launch_bounds__(1024) void k_scanB(int* __restrict__ segsum, int nseg) {
    int t = threadIdx.x;
    int v = (t < nseg) ? segsum[t] : 0;
    __shared__ int ps[1024];
    ps[t] = v;
    __syncthreads();
    for (int off = 1; off < 1024; off <<= 1) {
        int u = (t >= off) ? ps[t - off] : 0;
        __syncthreads();
        ps[t] += u;
        __syncthreads();
    }
    if (t < nseg) segsum[t] = ps[t] - v;
}

__global__ __launch_bounds__(256) void k_scanC(int* __restrict__ rowptr,
                                               const int* __restrict__ segsum,
                                               int* __restrict__ cursor, int M, int E) {
    int i = blockIdx.x * 256 + threadIdx.x;
    if (i < M) {
        int r = rowptr[i] + segsum[blockIdx.x];
        rowptr[i] = r;
        cursor[i] = r;
    }
    if (i == 0) rowptr[M] = E;
}

// ---------------- CSR fill: {src, weight}, grouped by (dst, src-bucket) ----------
__global__ __launch_bounds__(256) void k_fill4(const int* __restrict__ src,
                                               const int* __restrict__ dst,
                                               const float* __restrict__ dinv,
                                               int* __restrict__ cursor4,
                                               int2* __restrict__ csr, int E, int Q) {
    int e = blockIdx.x * 256 + threadIdx.x;
    if (e >= E) return;
    int s = src[e], d = dst[e];
    int p = src_bucket(s, Q);
    int pos = atomicAdd(&cursor4[(d << 2) + p], 1);
    float w = dinv[s] * dinv[d];
    csr[pos] = make_int2(s, __float_as_int(w));
}

// ---------------- MFMA GEMM: H(bf16) = (cvec +) f(X) @ W ----------------
template<bool RELU_IN, bool ADD_C>
__global__ __launch_bounds__(256) void k_gemm(const float* __restrict__ X,
                                              const float* __restrict__ W,
                                              const float* __restrict__ Cvec,
                                              ushort* __restrict__ H, int n) {
    __shared__ ushort sWT[DIM][WPAD];    // ~34 KB
    __shared__ ushort sX[4][16][WPAD];   // ~17.4 KB, per-wave tile
    const int tid = threadIdx.x;
    const int w = tid >> 6, l = tid & 63;
    const int col = l & 15;
    const int kg = l >> 4;

    for (int idx = tid; idx < DIM * DIM; idx += 256) {
        int k = idx >> 7, j = idx & 127;
        sWT[j][k] = f2bf(W[idx]);
    }
    float cj[8];
    if (ADD_C) {
        #pragma unroll
        for (int t = 0; t < 8; ++t) cj[t] = Cvec[t * 16 + col];
    }
    __syncthreads();

    for (int base = blockIdx.x * 64; base < n; base += gridDim.x * 64) {
        int i0 = base + w * 16;
        for (int idx = l; idx < 16 * 32; idx += 64) {
            int r = idx >> 5, c4 = idx & 31;
            float4 v = make_float4(0.f, 0.f, 0.f, 0.f);
            if (i0 + r < n) v = ((const float4*)(X + (size_t)(i0 + r) * DIM))[c4];
            if (RELU_IN) {
                v.x = fmaxf(v.x, 0.f); v.y = fmaxf(v.y, 0.f);
                v.z = fmaxf(v.z, 0.f); v.w = fmaxf(v.w, 0.f);
            }
            ushort* p = &sX[w][r][c4 * 4];
            p[0] = f2bf(v.x); p[1] = f2bf(v.y); p[2] = f2bf(v.z); p[3] = f2bf(v.w);
        }
        f32x4 acc[8];
        #pragma unroll
        for (int t = 0; t < 8; ++t) {
            float c0 = ADD_C ? cj[t] : 0.f;
            acc[t][0] = c0; acc[t][1] = c0; acc[t][2] = c0; acc[t][3] = c0;
        }
        #pragma unroll
        for (int k0 = 0; k0 < DIM; k0 += 32) {
            bf16x8 a = *(const bf16x8*)&sX[w][col][k0 + kg * 8];
            #pragma unroll
            for (int t = 0; t < 8; ++t) {
                bf16x8 b = *(const bf16x8*)&sWT[t * 16 + col][k0 + kg * 8];
                acc[t] = __builtin_amdgcn_mfma_f32_16x16x32_bf16(a, b, acc[t], 0, 0, 0);
            }
        }
        #pragma unroll
        for (int t = 0; t < 8; ++t) {
            #pragma unroll
            for (int r = 0; r < 4; ++r) {
                int row = i0 + kg * 4 + r;
                if (row < n) H[(size_t)row * DIM + t * 16 + col] = f2bf(acc[t][r]);
            }
        }
    }
}

// ---------------- c[j] = sum_k relu(posts[root][k]) * W2[k][j] ----------------
__global__ __launch_bounds__(DIM) void k_cvec(const float* __restrict__ posts,
                                              const int* __restrict__ root,
                                              const float* __restrict__ W2,
                                              float* __restrict__ cvec) {
    int j = threadIdx.x;
    const float* xr = posts + (size_t)root[0] * DIM;
    float acc = 0.0f;
    #pragma unroll 8
    for (int k = 0; k < DIM; ++k)
        acc = fmaf(fmaxf(xr[k], 0.0f), W2[k * DIM + j], acc);
    cvec[j] = acc;
}

// ---------------- wave-per-node segment accumulate (scalar csr, SGPR bases) -------
__device__ __forceinline__ void wave_accum(const int2* __restrict__ csr,
                                           int beg, int end, int q,
                                           const ushort* __restrict__ h,
                                           float& a0, float& a1) {
    int e = beg;
    for (; e + 16 <= end; e += 16) {
        int sc[16];
        float wt[16];
        #pragma unroll
        for (int u = 0; u < 16; ++u) {
            int2 c = csr[e + u];
            sc[u] = RFL(c.x);
            wt[u] = __int_as_float(RFL(c.y));
        }
        uint hv[16];
        #pragma unroll
        for (int u = 0; u < 16; ++u)
            hv[u] = ((const uint*)(h + (size_t)sc[u] * DIM))[q];
        #pragma unroll
        for (int u = 0; u < 16; ++u) {
            a0 = fmaf(__uint_as_float(hv[u] << 16), wt[u], a0);
            a1 = fmaf(__uint_as_float(hv[u] & 0xFFFF0000u), wt[u], a1);
        }
    }
    for (; e + 8 <= end; e += 8) {
        int sc[8];
        float wt[8];
        #pragma unroll
        for (int u = 0; u < 8; ++u) {
            int2 c = csr[e + u];
            sc[u] = RFL(c.x);
            wt[u] = __int_as_float(RFL(c.y));
        }
        uint hv[8];
        #pragma unroll
        for (int u = 0; u < 8; ++u)
            hv[u] = ((const uint*)(h + (size_t)sc[u] * DIM))[q];
        #pragma unroll
        for (int u = 0; u < 8; ++u) {
            a0 = fmaf(__uint_as_float(hv[u] << 16), wt[u], a0);
            a1 = fmaf(__uint_as_float(hv[u] & 0xFFFF0000u), wt[u], a1);
        }
    }
    int rem = end - e;
    if (rem > 0) {
        int sc[8];
        float wt[8];
        #pragma unroll
        for (int u = 0; u < 8; ++u) {
            int idx = e + u; idx = idx < end ? idx : end - 1;
            int2 c = csr[idx];
            sc[u] = RFL(c.x);
            wt[u] = (u < rem) ? __int_as_float(RFL(c.y)) : 0.f;
        }
        uint hv[8];
        #pragma unroll
        for (int u = 0; u < 8; ++u)
            hv[u] = ((const uint*)(h + (size_t)sc[u] * DIM))[q];
        #pragma unroll
        for (int u = 0; u < 8; ++u) {
            a0 = fmaf(__uint_as_float(hv[u] << 16), wt[u], a0);
            a1 = fmaf(__uint_as_float(hv[u] & 0xFFFF0000u), wt[u], a1);
        }
    }
}

// ---------------- gather layer 1, one src-bucket pass ----------------
// FIRST: conv1 = partial. MID: conv1 += partial. LAST: += self+bias, root out.
template<bool FIRST, bool LAST>
__global__ __launch_bounds__(256) void k_gather1(const int2* __restrict__ csr,
                                                 const int* __restrict__ rowptr4,
                                                 const float* __restrict__ dinv,
                                                 const ushort* __restrict__ h,
                                                 const float* __restrict__ b1,
                                                 const int* __restrict__ root,
                                                 float* __restrict__ conv1,
                                                 float* __restrict__ out, int N, int pass) {
    int q = threadIdx.x & 63;
    int wid = blockIdx.x * 4 + (threadIdx.x >> 6);
    int wstride = gridDim.x * 4;
    float2 bv = ((const float2*)b1)[q];
    int rt = RFL(root[0]);
    for (int d = wid; d < N; d += wstride) {
        int idx = (d << 2) + pass;
        int beg = RFL(rowptr4[idx]);
        int end = RFL(rowptr4[idx + 1]);
        float a0 = 0.f, a1 = 0.f;
        wave_accum(csr, beg, end, q, h, a0, a1);
        float2* crow = (float2*)(conv1 + (size_t)d * DIM) + q;
        float2 r = make_float2(a0, a1);
        if (!FIRST) {
            float2 c = *crow;
            r.x += c.x; r.y += c.y;
        }
        if (LAST) {
            float di = dinv[d], sl = di * di;
            uint hv = ((const uint*)(h + (size_t)d * DIM))[q];
            r.x = fmaf(__uint_as_float(hv << 16), sl, r.x) + bv.x;
            r.y = fmaf(__uint_as_float(hv & 0xFFFF0000u), sl, r.y) + bv.y;
        }
        *crow = r;
        if (LAST && d == rt) ((float2*)out)[q] = r;   // conv1_root (no relu)
    }
}

// ---------------- gather layer 2, one src-bucket pass (acc2 = reused conv1) -------
template<bool FIRST, bool LAST>
__global__ __launch_bounds__(256) void k_gather2(const int2* __restrict__ csr,
                                                 const int* __restrict__ rowptr4,
                                                 const float* __restrict__ dinv,
                                                 const ushort* __restrict__ h,
                                                 const float* __restrict__ b2,
                                                 float* __restrict__ acc2,
                                                 float* __restrict__ meanacc, int N, int pass) {
    int q = threadIdx.x & 63;
    int wid = blockIdx.x * 4 + (threadIdx.x >> 6);
    int wstride = gridDim.x * 4;
    float2 bv = ((const float2*)b2)[q];
    float s0 = 0.f, s1 = 0.f;
    for (int d = wid; d < N; d += wstride) {
        int idx = (d << 2) + pass;
        int beg = RFL(rowptr4[idx]);
        int end = RFL(rowptr4[idx + 1]);
        float a0 = 0.f, a1 = 0.f;
        wave_accum(csr, beg, end, q, h, a0, a1);
        float2* crow = (float2*)(acc2 + (size_t)d * DIM) + q;
        float2 r = make_float2(a0, a1);
        if (!FIRST) {
            float2 c = *crow;
            r.x += c.x; r.y += c.y;
        }
        if (!LAST) {
            *crow = r;
        } else {
            float di = dinv[d], sl = di * di;
            uint hv = ((const uint*)(h + (size_t)d * DIM))[q];
            s0 += fmaxf(fmaf(__uint_as_float(hv << 16), sl, r.x) + bv.x, 0.f);
            s1 += fmaxf(fmaf(__uint_as_float(hv & 0xFFFF0000u), sl, r.y) + bv.y, 0.f);
        }
    }
    if (LAST) {
        __shared__ float2 sp[256];
        sp[threadIdx.x] = make_float2(s0, s1);
        __syncthreads();
        if (threadIdx.x < 64) {
            float2 s = sp[threadIdx.x];
            #pragma unroll
            for (int g = 1; g < 4; ++g) {
                float2 o = sp[g * 64 + threadIdx.x];
                s.x += o.x; s.y += o.y;
            }
            unsafeAtomicAdd(&meanacc[q * 2 + 0], s.x);
            unsafeAtomicAdd(&meanacc[q * 2 + 1], s.y);
        }
    }
}

__global__ __launch_bounds__(DIM) void k_reduce(const float* __restrict__ meanacc,
                                                float* __restrict__ out, int N) {
    int j = threadIdx.x;
    out[DIM + j] = meanacc[j] / (float)N;
}

extern "C" void kernel_launch(void* const* d_in, const int* in_sizes, int n_in,
                              void* d_out, int out_size, void* d_ws, size_t ws_size,
                              hipStream_t stream) {
    const float* posts = (const float*)d_in[0];
    const int*   eidx  = (const int*)d_in[1];
    const int*   root  = (const int*)d_in[2];
    const float* W1    = (const float*)d_in[3];
    const float* b1    = (const float*)d_in[4];
    const float* W2    = (const float*)d_in[5];
    const float* b2    = (const float*)d_in[6];
    float* out = (float*)d_out;

    int N = in_sizes[0] / DIM;
    int E = in_sizes[1] / 2;
    int Q = (N + 3) / 4;          // src-quartile width (~3.2 MB bf16 h-slice)
    const int* src = eidx;
    const int* dst = eidx + E;
    int M = N * 4;
    int nseg4 = (M + 255) / 256;  // 782 for N=50000 (fits k_scanB's 1024)

    char* ws = (char*)d_ws;
    size_t off = 0;
    auto alloc = [&](size_t bytes) {
        void* p = ws + off;
        off += (bytes + 511) & ~(size_t)511;
        return p;
    };
    int*    deg4    = (int*)   alloc((size_t)M * 4);
    int*    rowptr4 = (int*)   alloc(((size_t)M + 1) * 4);
    int*    cursor4 = (int*)   alloc((size_t)M * 4);
    int*    segsum  = (int*)   alloc((size_t)nseg4 * 4);
    float*  dinv    = (float*) alloc((size_t)N * 4);
    float*  cvec    = (float*) alloc(DIM * 4);
    float*  meanacc = (float*) alloc(DIM * 4);
    int2*   csr     = (int2*)  alloc((size_t)E * 8);
    ushort* h       = (ushort*)alloc((size_t)N * DIM * 2);   // bf16 h1, then h2
    float*  conv1   = (float*) alloc((size_t)N * DIM * 4);   // conv1 accum / conv2 accum

    hipMemsetAsync(deg4, 0, (size_t)M * 4, stream);
    hipMemsetAsync(meanacc, 0, DIM * 4, stream);

    // CSR build: 4 src-quartile buckets per dst; parallel 3-stage scan
    k_count4<<<(E + 255) / 256, 256, 0, stream>>>(src, dst, deg4, E, Q);
    k_scanA<<<nseg4, 256, 0, stream>>>(deg4, rowptr4, segsum, M);
    k_scanB<<<1, 1024, 0, stream>>>(segsum, nseg4);
    k_scanC<<<nseg4, 256, 0, stream>>>(rowptr4, segsum, cursor4, M, E);
    k_dinv<<<(N + 255) / 256, 256, 0, stream>>>(rowptr4, dinv, N);
    k_fill4<<<(E + 255) / 256, 256, 0, stream>>>(src, dst, dinv, cursor4, csr, E, Q);

    // layer 1
    k_gemm<false, false><<<256, 256, 0, stream>>>(posts, W1, nullptr, h, N);
    k_gather1<true,  false><<<2048, 256, 0, stream>>>(csr, rowptr4, dinv, h, b1, root, conv1, out, N, 0);
    k_gather1<false, false><<<2048, 256, 0, stream>>>(csr, rowptr4, dinv, h, b1, root, conv1, out, N, 1);
    k_gather1<false, false><<<2048, 256, 0, stream>>>(csr, rowptr4, dinv, h, b1, root, conv1, out, N, 2);
    k_gather1<false, true ><<<2048, 256, 0, stream>>>(csr, rowptr4, dinv, h, b1, root, conv1, out, N, 3);

    // layer 2: h2 = cvec + relu(conv1) @ W2[128:], cvec = relu(post_root) @ W2[:128]
    k_cvec<<<1, DIM, 0, stream>>>(posts, root, W2, cvec);
    k_gemm<true, true><<<256, 256, 0, stream>>>(conv1, W2 + DIM * DIM, cvec, h, N);
    // conv1 buffer now free -> conv2 accumulator
    k_gather2<true,  false><<<2048, 256, 0, stream>>>(csr, rowptr4, dinv, h, b2, conv1, meanacc, N, 0);
    k_gather2<false, false><<<2048, 256, 0, stream>>>(csr, rowptr4, dinv, h, b2, conv1, meanacc, N, 1);
    k_gather2<false, false><<<2048, 256, 0, stream>>>(csr, rowptr4, dinv, h, b2, conv1, meanacc, N, 2);
    k_gather2<false, true ><<<2048, 256, 0, stream>>>(csr, rowptr4, dinv, h, b2, conv1, meanacc, N, 3);
    k_reduce<<<1, DIM, 0, stream>>>(meanacc, out, N);
}

// Round 17
// 300.529 us; speedup vs baseline: 1.2342x; 1.2342x over previous
//
#include <hip/hip_runtime.h>

#define DIM 128
#define WPAD 136   // DIM + 8 ushorts pad -> 16B-aligned rows, 2-way-free banks
typedef unsigned int uint;
typedef unsigned short ushort;

#define RFL __builtin_amdgcn_readfirstlane

typedef __attribute__((ext_vector_type(8))) short bf16x8;
typedef __attribute__((ext_vector_type(4))) float f32x4;

// bf16 pack (RNE)
__device__ __forceinline__ ushort f2bf(float x) {
    uint u = __float_as_uint(x);
    u = u + 0x7FFFu + ((u >> 16) & 1u);
    return (ushort)(u >> 16);
}

// ---------------- degree count ----------------
__global__ __launch_bounds__(256) void k_count(const int* __restrict__ dst,
                                               int* __restrict__ deg, int E) {
    int t = blockIdx.x * 256 + threadIdx.x;
    if (t < E) atomicAdd(&deg[dst[t]], 1);
}

__global__ __launch_bounds__(256) void k_dinv(const int* __restrict__ deg,
                                              float* __restrict__ dinv, int N) {
    int t = blockIdx.x * 256 + threadIdx.x;
    if (t < N) dinv[t] = rsqrtf((float)(deg[t] + 1));  // +1 = self-loop
}

// ---------------- parallel exclusive scan: blockwise -> seg -> add ----------------
__global__ __launch_bounds__(256) void k_scanA(const int* __restrict__ deg,
                                               int* __restrict__ rowptr,
                                               int* __restrict__ segsum, int N) {
    int i = blockIdx.x * 256 + threadIdx.x;
    int v = (i < N) ? deg[i] : 0;
    __shared__ int ps[256];
    ps[threadIdx.x] = v;
    __syncthreads();
    for (int off = 1; off < 256; off <<= 1) {
        int u = (threadIdx.x >= off) ? ps[threadIdx.x - off] : 0;
        __syncthreads();
        ps[threadIdx.x] += u;
        __syncthreads();
    }
    if (i < N) rowptr[i] = ps[threadIdx.x] - v;   // exclusive within block
    if (threadIdx.x == 255) segsum[blockIdx.x] = ps[255];
}

__global__ __launch_bounds__(256) void k_scanB(int* __restrict__ segsum, int nseg) {
    int t = threadIdx.x;
    int v = (t < nseg) ? segsum[t] : 0;
    __shared__ int ps[256];
    ps[t] = v;
    __syncthreads();
    for (int off = 1; off < 256; off <<= 1) {
        int u = (t >= off) ? ps[t - off] : 0;
        __syncthreads();
        ps[t] += u;
        __syncthreads();
    }
    if (t < nseg) segsum[t] = ps[t] - v;
}

__global__ __launch_bounds__(256) void k_scanC(int* __restrict__ rowptr,
                                               const int* __restrict__ segsum,
                                               int* __restrict__ cursor, int N, int E) {
    int i = blockIdx.x * 256 + threadIdx.x;
    if (i < N) {
        int r = rowptr[i] + segsum[blockIdx.x];
        rowptr[i] = r;
        cursor[i] = r;
    }
    if (i == 0) rowptr[N] = E;
}

// ---------------- CSR fill: {src, weight} per edge, grouped by dst ----------------
__global__ __launch_bounds__(256) void k_fill(const int* __restrict__ src,
                                              const int* __restrict__ dst,
                                              const float* __restrict__ dinv,
                                              int* __restrict__ cursor,
                                              int2* __restrict__ csr, int E) {
    int e = blockIdx.x * 256 + threadIdx.x;
    if (e >= E) return;
    int s = src[e], d = dst[e];
    int p = atomicAdd(&cursor[d], 1);
    float w = dinv[s] * dinv[d];
    csr[p] = make_int2(s, __float_as_int(w));
}

// ---------------- MFMA GEMM: H(bf16) = (cvec +) f(X) @ W ----------------
// W^T staged bf16 in LDS [j][k] once per block; X tiles per-wave bf16.
// v_mfma_f32_16x16x32_bf16 fragments (HW-verified layouts):
//   A: row=lane&15, k=(lane>>4)*8+i  (8 contiguous bf16 -> ds_read_b128)
//   B: col=lane&15, k=(lane>>4)*8+i  (contiguous in k via W^T layout)
//   C/D: col=lane&15, row=(lane>>4)*4+reg
template<bool RELU_IN, bool ADD_C>
__global__ __launch_bounds__(256) void k_gemm(const float* __restrict__ X,
                                              const float* __restrict__ W,
                                              const float* __restrict__ Cvec,
                                              ushort* __restrict__ H, int n) {
    __shared__ ushort sWT[DIM][WPAD];    // ~34 KB
    __shared__ ushort sX[4][16][WPAD];   // ~17.4 KB, per-wave tile
    const int tid = threadIdx.x;
    const int w = tid >> 6, l = tid & 63;
    const int col = l & 15;   // A-row / B-col / D-col selector
    const int kg = l >> 4;    // 0..3 k-group

    for (int idx = tid; idx < DIM * DIM; idx += 256) {
        int k = idx >> 7, j = idx & 127;     // coalesced read W[k][j]
        sWT[j][k] = f2bf(W[idx]);
    }
    float cj[8];
    if (ADD_C) {
        #pragma unroll
        for (int t = 0; t < 8; ++t) cj[t] = Cvec[t * 16 + col];
    }
    __syncthreads();

    for (int base = blockIdx.x * 64; base < n; base += gridDim.x * 64) {
        int i0 = base + w * 16;
        // stage 16 rows -> bf16 (relu fused); per-wave region, no barrier needed
        for (int idx = l; idx < 16 * 32; idx += 64) {
            int r = idx >> 5, c4 = idx & 31;
            float4 v = make_float4(0.f, 0.f, 0.f, 0.f);
            if (i0 + r < n) v = ((const float4*)(X + (size_t)(i0 + r) * DIM))[c4];
            if (RELU_IN) {
                v.x = fmaxf(v.x, 0.f); v.y = fmaxf(v.y, 0.f);
                v.z = fmaxf(v.z, 0.f); v.w = fmaxf(v.w, 0.f);
            }
            ushort* p = &sX[w][r][c4 * 4];
            p[0] = f2bf(v.x); p[1] = f2bf(v.y); p[2] = f2bf(v.z); p[3] = f2bf(v.w);
        }
        f32x4 acc[8];
        #pragma unroll
        for (int t = 0; t < 8; ++t) {
            float c0 = ADD_C ? cj[t] : 0.f;
            acc[t][0] = c0; acc[t][1] = c0; acc[t][2] = c0; acc[t][3] = c0;
        }
        #pragma unroll
        for (int k0 = 0; k0 < DIM; k0 += 32) {
            bf16x8 a = *(const bf16x8*)&sX[w][col][k0 + kg * 8];
            #pragma unroll
            for (int t = 0; t < 8; ++t) {
                bf16x8 b = *(const bf16x8*)&sWT[t * 16 + col][k0 + kg * 8];
                acc[t] = __builtin_amdgcn_mfma_f32_16x16x32_bf16(a, b, acc[t], 0, 0, 0);
            }
        }
        #pragma unroll
        for (int t = 0; t < 8; ++t) {
            #pragma unroll
            for (int r = 0; r < 4; ++r) {
                int row = i0 + kg * 4 + r;
                if (row < n) H[(size_t)row * DIM + t * 16 + col] = f2bf(acc[t][r]);
            }
        }
    }
}

// ---------------- c[j] = sum_k relu(posts[root][k]) * W2[k][j] ----------------
__global__ __launch_bounds__(DIM) void k_cvec(const float* __restrict__ posts,
                                              const int* __restrict__ root,
                                              const float* __restrict__ W2,
                                              float* __restrict__ cvec) {
    int j = threadIdx.x;
    const float* xr = posts + (size_t)root[0] * DIM;
    float acc = 0.0f;
    #pragma unroll 8
    for (int k = 0; k < DIM; ++k)
        acc = fmaf(fmaxf(xr[k], 0.0f), W2[k * DIM + j], acc);
    cvec[j] = acc;
}

// ---------------- wave-per-node gather: scalar csr loads, SGPR row bases ----------
__device__ __forceinline__ void wave_accum(const int2* __restrict__ csr,
                                           int beg, int end, int q,
                                           const ushort* __restrict__ h,
                                           float& a0, float& a1) {
    int e = beg;
    for (; e + 16 <= end; e += 16) {
        int sc[16];
        float wt[16];
        #pragma unroll
        for (int u = 0; u < 16; ++u) {
            int2 c = csr[e + u];
            sc[u] = RFL(c.x);
            wt[u] = __int_as_float(RFL(c.y));
        }
        uint hv[16];
        #pragma unroll
        for (int u = 0; u < 16; ++u)
            hv[u] = ((const uint*)(h + (size_t)sc[u] * DIM))[q];
        #pragma unroll
        for (int u = 0; u < 16; ++u) {
            a0 = fmaf(__uint_as_float(hv[u] << 16), wt[u], a0);
            a1 = fmaf(__uint_as_float(hv[u] & 0xFFFF0000u), wt[u], a1);
        }
    }
    for (; e + 8 <= end; e += 8) {
        int sc[8];
        float wt[8];
        #pragma unroll
        for (int u = 0; u < 8; ++u) {
            int2 c = csr[e + u];
            sc[u] = RFL(c.x);
            wt[u] = __int_as_float(RFL(c.y));
        }
        uint hv[8];
        #pragma unroll
        for (int u = 0; u < 8; ++u)
            hv[u] = ((const uint*)(h + (size_t)sc[u] * DIM))[q];
        #pragma unroll
        for (int u = 0; u < 8; ++u) {
            a0 = fmaf(__uint_as_float(hv[u] << 16), wt[u], a0);
            a1 = fmaf(__uint_as_float(hv[u] & 0xFFFF0000u), wt[u], a1);
        }
    }
    int rem = end - e;
    if (rem > 0) {
        int sc[8];
        float wt[8];
        #pragma unroll
        for (int u = 0; u < 8; ++u) {
            int idx = e + u; idx = idx < end ? idx : end - 1;
            int2 c = csr[idx];
            sc[u] = RFL(c.x);
            wt[u] = (u < rem) ? __int_as_float(RFL(c.y)) : 0.f;
        }
        uint hv[8];
        #pragma unroll
        for (int u = 0; u < 8; ++u)
            hv[u] = ((const uint*)(h + (size_t)sc[u] * DIM))[q];
        #pragma unroll
        for (int u = 0; u < 8; ++u) {
            a0 = fmaf(__uint_as_float(hv[u] << 16), wt[u], a0);
            a1 = fmaf(__uint_as_float(hv[u] & 0xFFFF0000u), wt[u], a1);
        }
    }
}

// ---------------- gather layer 1: conv1(f32) = A_norm @ h + self + b1 ----------------
__global__ __launch_bounds__(256) void k_gather1(const int2* __restrict__ csr,
                                                 const int* __restrict__ rowptr,
                                                 const float* __restrict__ dinv,
                                                 const ushort* __restrict__ h,
                                                 const float* __restrict__ b1,
                                                 const int* __restrict__ root,
                                                 float* __restrict__ conv1,
                                                 float* __restrict__ out, int N) {
    int q = threadIdx.x & 63;
    int wid = blockIdx.x * 4 + (threadIdx.x >> 6);
    int wstride = gridDim.x * 4;
    float2 bv = ((const float2*)b1)[q];
    int rt = RFL(root[0]);
    for (int d = wid; d < N; d += wstride) {
        int beg = RFL(rowptr[d]);
        int end = RFL(rowptr[d + 1]);
        float a0 = 0.f, a1 = 0.f;
        wave_accum(csr, beg, end, q, h, a0, a1);
        float di = dinv[d], sl = di * di;
        uint hv = ((const uint*)(h + (size_t)d * DIM))[q];
        float2 r;
        r.x = fmaf(__uint_as_float(hv << 16), sl, a0) + bv.x;
        r.y = fmaf(__uint_as_float(hv & 0xFFFF0000u), sl, a1) + bv.y;
        ((float2*)(conv1 + (size_t)d * DIM))[q] = r;
        if (d == rt) ((float2*)out)[q] = r;   // conv1_root (no relu)
    }
}

// ---------------- gather layer 2 + relu + fused column-mean ----------------
__global__ __launch_bounds__(256) void k_gather2(const int2* __restrict__ csr,
                                                 const int* __restrict__ rowptr,
                                                 const float* __restrict__ dinv,
                                                 const ushort* __restrict__ h,
                                                 const float* __restrict__ b2,
                                                 float* __restrict__ meanacc, int N) {
    int q = threadIdx.x & 63;
    int wid = blockIdx.x * 4 + (threadIdx.x >> 6);
    int wstride = gridDim.x * 4;
    float2 bv = ((const float2*)b2)[q];
    float s0 = 0.f, s1 = 0.f;   // running column sums for cols 2q, 2q+1
    for (int d = wid; d < N; d += wstride) {
        int beg = RFL(rowptr[d]);
        int end = RFL(rowptr[d + 1]);
        float a0 = 0.f, a1 = 0.f;
        wave_accum(csr, beg, end, q, h, a0, a1);
        float di = dinv[d], sl = di * di;
        uint hv = ((const uint*)(h + (size_t)d * DIM))[q];
        s0 += fmaxf(fmaf(__uint_as_float(hv << 16), sl, a0) + bv.x, 0.f);
        s1 += fmaxf(fmaf(__uint_as_float(hv & 0xFFFF0000u), sl, a1) + bv.y, 0.f);
    }
    __shared__ float2 sp[256];
    sp[threadIdx.x] = make_float2(s0, s1);
    __syncthreads();
    if (threadIdx.x < 64) {
        float2 s = sp[threadIdx.x];
        #pragma unroll
        for (int g = 1; g < 4; ++g) {
            float2 o = sp[g * 64 + threadIdx.x];
            s.x += o.x; s.y += o.y;
        }
        unsafeAtomicAdd(&meanacc[q * 2 + 0], s.x);
        unsafeAtomicAdd(&meanacc[q * 2 + 1], s.y);
    }
}

__global__ __launch_bounds__(DIM) void k_reduce(const float* __restrict__ meanacc,
                                                float* __restrict__ out, int N) {
    int j = threadIdx.x;
    out[DIM + j] = meanacc[j] / (float)N;
}

extern "C" void kernel_launch(void* const* d_in, const int* in_sizes, int n_in,
                              void* d_out, int out_size, void* d_ws, size_t ws_size,
                              hipStream_t stream) {
    const float* posts = (const float*)d_in[0];
    const int*   eidx  = (const int*)d_in[1];
    const int*   root  = (const int*)d_in[2];
    const float* W1    = (const float*)d_in[3];
    const float* b1    = (const float*)d_in[4];
    const float* W2    = (const float*)d_in[5];
    const float* b2    = (const float*)d_in[6];
    float* out = (float*)d_out;

    int N = in_sizes[0] / DIM;
    int E = in_sizes[1] / 2;
    const int* src = eidx;
    const int* dst = eidx + E;
    int nseg = (N + 255) / 256;   // 196 for N=50000 (fits k_scanB's 256)

    char* ws = (char*)d_ws;
    size_t off = 0;
    auto alloc = [&](size_t bytes) {
        void* p = ws + off;
        off += (bytes + 511) & ~(size_t)511;
        return p;
    };
    int*    deg     = (int*)   alloc((size_t)N * 4);
    int*    rowptr  = (int*)   alloc((size_t)(N + 1) * 4);
    int*    cursor  = (int*)   alloc((size_t)N * 4);
    int*    segsum  = (int*)   alloc((size_t)nseg * 4);
    float*  dinv    = (float*) alloc((size_t)N * 4);
    float*  cvec    = (float*) alloc(DIM * 4);
    float*  meanacc = (float*) alloc(DIM * 4);
    int2*   csr     = (int2*)  alloc((size_t)E * 8);
    ushort* h       = (ushort*)alloc((size_t)N * DIM * 2);   // bf16 h1, then h2
    float*  conv1   = (float*) alloc((size_t)N * DIM * 4);   // conv1_out (f32)

    hipMemsetAsync(deg, 0, (size_t)N * 4, stream);
    hipMemsetAsync(meanacc, 0, DIM * 4, stream);

    // CSR build (once, shared by both layers); parallel 3-stage scan
    k_count<<<(E + 255) / 256, 256, 0, stream>>>(dst, deg, E);
    k_scanA<<<nseg, 256, 0, stream>>>(deg, rowptr, segsum, N);
    k_scanB<<<1, 256, 0, stream>>>(segsum, nseg);
    k_scanC<<<nseg, 256, 0, stream>>>(rowptr, segsum, cursor, N, E);
    k_dinv<<<(N + 255) / 256, 256, 0, stream>>>(deg, dinv, N);
    k_fill<<<(E + 255) / 256, 256, 0, stream>>>(src, dst, dinv, cursor, csr, E);

    // layer 1
    k_gemm<false, false><<<256, 256, 0, stream>>>(posts, W1, nullptr, h, N);
    k_gather1<<<2048, 256, 0, stream>>>(csr, rowptr, dinv, h, b1, root, conv1, out, N);

    // layer 2: h2 = cvec + relu(conv1) @ W2[128:], cvec = relu(post_root) @ W2[:128]
    k_cvec<<<1, DIM, 0, stream>>>(posts, root, W2, cvec);
    k_gemm<true, true><<<256, 256, 0, stream>>>(conv1, W2 + DIM * DIM, cvec, h, N);
    k_gather2<<<2048, 256, 0, stream>>>(csr, rowptr, dinv, h, b2, meanacc, N);
    k_reduce<<<1, DIM, 0, stream>>>(meanacc, out, N);
}